// Round 4
// baseline (1535.033 us; speedup 1.0000x reference)
//
#include <hip/hip_runtime.h>

#define D   2048
#define S   2048
#define NQ  16384
#define DD  ((long)D * (long)D)

// ---- ws small-region layout (float indices) ----
#define IDX_N      0        // [2] class counts (atomic)
#define IDX_NORMS  16       // [2][16] power-iter norms (atomic)
#define IDX_S      48       // [2] mu^T P mu
#define IDX_SUM    256      // [2][2048] masked column sums (atomic)
#define IDX_MU     4608     // [2][2048] class means
#define IDX_MUF    8704     // [2048]   full mean
#define IDX_U      10752    // [2][2048] u = P mu
#define IDX_V      14848    // [2][2048] power vec ping
#define IDX_W2     18944    // [2][2048] power vec pong
#define IDX_ACC    32768    // [16384][2] logits accumulator (atomic)
#define SMALL_FLOATS 65536  // 256 KB zeroed region

#define NPOW 8
#define NNS  5

typedef unsigned short u16;
typedef __attribute__((ext_vector_type(8))) short short8;
typedef __attribute__((ext_vector_type(4))) short short4v;
typedef __attribute__((ext_vector_type(4))) float f32x4;

__device__ __forceinline__ u16 f2bf(float f) {
    unsigned u = __float_as_uint(f);
    u += 0x7fff + ((u >> 16) & 1);
    return (u16)(u >> 16);
}

__device__ __forceinline__ void gl16(const void* g, void* l) {
    __builtin_amdgcn_global_load_lds((const __attribute__((address_space(1))) void*)g,
                                     (__attribute__((address_space(3))) void*)l, 16, 0, 0);
}

// ---------------- small kernels ----------------

__global__ void k_counts(const int* __restrict__ lab, float* __restrict__ W) {
    int c0 = 0, c1 = 0;
    for (int i = threadIdx.x; i < S; i += 256) {
        int l = lab[i];
        c0 += (l == 0);
        c1 += (l == 1);
    }
    atomicAdd(&W[IDX_N + 0], (float)c0);
    atomicAdd(&W[IDX_N + 1], (float)c1);
}

__global__ void k_colsums(const float* __restrict__ X, const int* __restrict__ lab,
                          float* __restrict__ W) {
    int d  = blockIdx.x * 256 + threadIdx.x;
    int i0 = blockIdx.y * 128;
    float s0 = 0.f, s1 = 0.f;
    for (int i = i0; i < i0 + 128; ++i) {
        float v = X[(long)i * D + d];
        int   l = lab[i];
        s0 += (l == 0) ? v : 0.f;
        s1 += (l == 1) ? v : 0.f;
    }
    atomicAdd(&W[IDX_SUM + d],     s0);
    atomicAdd(&W[IDX_SUM + D + d], s1);
}

__global__ void k_stats(float* __restrict__ W) {
    int d = blockIdx.x * 256 + threadIdx.x;
    float n0 = W[IDX_N], n1 = W[IDX_N + 1];
    float s0 = W[IDX_SUM + d], s1 = W[IDX_SUM + D + d];
    W[IDX_MU + d]     = s0 / n0;
    W[IDX_MU + D + d] = s1 / n1;
    W[IDX_MUF + d]    = (s0 + s1) / (float)S;
    unsigned h = (unsigned)d * 2654435761u;
    float r = 0.5f + (float)((h >> 16) & 1023) / 1024.f;
    W[IDX_V + d]     = r;
    W[IDX_V + D + d] = r;
}

__global__ void k_build_M(float* __restrict__ AM, const float* __restrict__ W) {
    long idx = (long)blockIdx.x * 256 + threadIdx.x;
    int d = (int)(idx / D), e = (int)(idx % D);
    float n0 = W[IDX_N], n1 = W[IDX_N + 1];
    float mufd = W[IDX_MUF + d],     mufe = W[IDX_MUF + e];
    float m0d  = W[IDX_MU + d],      m0e  = W[IDX_MU + e];
    float m1d  = W[IDX_MU + D + d],  m1e  = W[IDX_MU + D + e];
    float a0 = AM[idx], a1 = AM[DD + idx];
    float task = (a0 + a1 - (float)S * mufd * mufe) * (1.f / (float)(S - 1));
    float c0 = (a0 - n0 * m0d * m0e) / (n0 - 1.f);
    float c1 = (a1 - n1 * m1d * m1e) / (n1 - 1.f);
    float l0 = fminf(n0 / (n0 + 1.f), 0.1f);
    float l1 = fminf(n1 / (n1 + 1.f), 0.1f);
    float eye = (d == e) ? 0.1f : 0.f;
    AM[idx]      = l0 * c0 + (1.f - l0) * task + eye;
    AM[DD + idx] = l1 * c1 + (1.f - l1) * task + eye;
}

__global__ void k_pow(const float* __restrict__ Mm, float* __restrict__ W, int it) {
    int z = blockIdx.y;
    const float* Mz = Mm + (long)z * DD;
    float* V  = W + IDX_V  + z * D;
    float* W2 = W + IDX_W2 + z * D;
    const float* in = (it & 1) ? W2 : V;
    float*       out = (it & 1) ? V  : W2;
    float sc = (it > 0) ? rsqrtf(W[IDX_NORMS + z * 16 + it - 1]) : 1.f;
    int wv = threadIdx.x >> 6, ln = threadIdx.x & 63;
    int d = blockIdx.x * 4 + wv;
    float p = 0.f;
    for (int e = ln; e < D; e += 64) p += Mz[(long)d * D + e] * in[e];
    for (int off = 32; off; off >>= 1) p += __shfl_down(p, off);
    if (ln == 0) {
        float w = p * sc;
        out[d] = w;
        atomicAdd(&W[IDX_NORMS + z * 16 + it], w * w);
    }
}

__global__ void k_matvec_u(const float* __restrict__ P, float* __restrict__ W) {
    int z = blockIdx.y;
    const float* Pz = P + (long)z * DD;
    const float* mu = W + IDX_MU + z * D;
    int wv = threadIdx.x >> 6, ln = threadIdx.x & 63;
    int d = blockIdx.x * 4 + wv;
    float p = 0.f;
    for (int e = ln; e < D; e += 64) p += Pz[(long)d * D + e] * mu[e];
    for (int off = 32; off; off >>= 1) p += __shfl_down(p, off);
    if (ln == 0) W[IDX_U + z * D + d] = p;
}

__global__ void k_dot(float* __restrict__ W) {
    int z = blockIdx.x;
    float t = 0.f;
    for (int d = threadIdx.x; d < D; d += 256)
        t += W[IDX_MU + z * D + d] * W[IDX_U + z * D + d];
    for (int off = 32; off; off >>= 1) t += __shfl_down(t, off);
    __shared__ float sm[4];
    int wv = threadIdx.x >> 6, ln = threadIdx.x & 63;
    if (ln == 0) sm[wv] = t;
    __syncthreads();
    if (threadIdx.x == 0) W[IDX_S + z] = sm[0] + sm[1] + sm[2] + sm[3];
}

__global__ void k_finalize(const float* __restrict__ W, float* __restrict__ out) {
    int idx = blockIdx.x * 256 + threadIdx.x;
    int z = idx & 1;
    out[idx] = -(W[IDX_ACC + idx] + W[IDX_S + z]);
}

// ---------------- pack kernels (k-packed bf16 layout: [K/8][cols][8]) ----------------

__global__ void k_pack_S(const float* __restrict__ Xs, const int* __restrict__ lab,
                         u16* __restrict__ Sp, u16* __restrict__ S01p) {
    int d = blockIdx.x * 256 + threadIdx.x;
    int a = blockIdx.y;                 // row-group i/8
    short8 p, p0, p1;
#pragma unroll
    for (int j = 0; j < 8; ++j) {
        int i = a * 8 + j;
        float v = Xs[(long)i * D + d];
        int   l = lab[i];
        short b = (short)f2bf(v);
        p[j]  = b;
        p0[j] = (l == 0) ? b : (short)0;
        p1[j] = (l == 1) ? b : (short)0;
    }
    long off = ((long)a * D + d) * 8;
    *(short8*)&Sp[off]        = p;
    *(short8*)&S01p[off]      = p0;
    *(short8*)&S01p[DD + off] = p1;
}

__global__ void k_pack_M(const float* __restrict__ Mf, u16* __restrict__ Mp) {
    int c = blockIdx.x * 256 + threadIdx.x;
    int a = blockIdx.y;
    int z = blockIdx.z;
    const float* src = Mf + (long)z * DD;
    u16* dst = Mp + (long)z * DD;
    short8 pk;
#pragma unroll
    for (int j = 0; j < 8; ++j) pk[j] = (short)f2bf(src[(long)(a * 8 + j) * D + c]);
    *(short8*)&dst[((long)a * D + c) * 8] = pk;
}

__global__ void k_pack_Q(const float* __restrict__ Q, u16* __restrict__ Qp) {
    int m = blockIdx.x;
    int t = threadIdx.x;                // k-group
    const float* row = Q + (long)m * D + t * 8;
    float4 v0 = *(const float4*)row;
    float4 v1 = *(const float4*)(row + 4);
    short8 pk;
    pk[0] = (short)f2bf(v0.x); pk[1] = (short)f2bf(v0.y);
    pk[2] = (short)f2bf(v0.z); pk[3] = (short)f2bf(v0.w);
    pk[4] = (short)f2bf(v1.x); pk[5] = (short)f2bf(v1.y);
    pk[6] = (short)f2bf(v1.z); pk[7] = (short)f2bf(v1.w);
    *(short8*)&Qp[((long)t * NQ + m) * 8] = pk;
}

// ---------------- bf16 MFMA GEMM, 256x256 tile, counted-vmcnt pipeline ----------------
// 512 threads = 8 waves (2M x 4N), per-wave 128x64 output, BK=32 per half-step.
// LDS: 4-slot ring, slot = A-half (4kg x 256 x 8 = 16KB) + B-half (16KB) = 32KB; 128KB total.
// Pipeline: 3 half-tiles prefetched via global_load_lds; main loop waits vmcnt(8)
// (counted, never 0), raw s_barrier, issues next half, computes current.
// EPI: 0=store fp32 C; 1=pack(I-acc); 2=X+=acc (fp32 RMW)+pack; 3=fused logits;
// 4=Chebyshev init X0=C0 I+C1 M+C2 acc (fp32 over Ef)+pack.
template <int EPI>
__global__ void __launch_bounds__(512)
bgemm2(const u16* __restrict__ Ap, const u16* __restrict__ Bp,
       float* __restrict__ Cf, u16* __restrict__ Cp, float* __restrict__ Ef,
       long sA, long sB, long sCf, long sCp,
       int lda, int K,
       const float* __restrict__ u, float* __restrict__ acc2,
       const float* __restrict__ Qf) {
    int z = blockIdx.z;
    const u16* A = Ap + z * sA;
    const u16* B = Bp + z * sB;

    // T1: bijective XCD swizzle over the per-z 2D grid (nwg % 8 == 0 for all our grids)
    int nwg = gridDim.x * gridDim.y;
    int id  = blockIdx.y * gridDim.x + blockIdx.x;
    int cpx = nwg >> 3;
    int swz = (id & 7) * cpx + (id >> 3);
    int bx = swz % gridDim.x, by = swz / gridDim.x;

    int n0 = bx * 256;
    int m0 = by * 256;
    int tid = threadIdx.x;
    int w = tid >> 6, lane = tid & 63;
    int wr = w >> 2, wc = w & 3;           // 2 x 4 wave grid
    int lhi = lane >> 4, llo = lane & 15;

    __shared__ short lds[65536];           // 128 KB

    f32x4 acc[8][4];
#pragma unroll
    for (int i = 0; i < 8; ++i)
#pragma unroll
        for (int j = 0; j < 4; ++j) acc[i][j] = (f32x4)(0.f);

    // stage half-tile H (kgroups 4H..4H+3) into ring slot H&3; 4 gl16 per wave
    auto stage = [&](int H) {
        char* ldsB = (char*)lds + (H & 3) * 32768;
#pragma unroll
        for (int q = 0; q < 4; ++q) {
            int id4  = w * 4 + q;          // 0..31 slabs
            int isB  = id4 >> 4;
            int kg   = (id4 >> 2) & 3;
            int colq = id4 & 3;
            long row = (long)(4 * H + kg);
            const u16* src = isB ? (B + (row * (long)D   + n0 + colq * 64) * 8)
                                 : (A + (row * (long)lda + m0 + colq * 64) * 8);
            gl16((const char*)src + lane * 16,
                 ldsB + isB * 16384 + kg * 4096 + colq * 1024);
        }
    };

    auto compute = [&](int h) {
        const short* As = lds + (h & 3) * 16384 + lhi * 2048;
        const short* Bs = As + 8192;
        short8 af[8], bfr[4];
#pragma unroll
        for (int i = 0; i < 8; ++i)
            af[i] = *(const short8*)&As[(wr * 128 + i * 16 + llo) * 8];
#pragma unroll
        for (int j = 0; j < 4; ++j)
            bfr[j] = *(const short8*)&Bs[(wc * 64 + j * 16 + llo) * 8];
        __builtin_amdgcn_s_setprio(1);
#pragma unroll
        for (int i = 0; i < 8; ++i)
#pragma unroll
            for (int j = 0; j < 4; ++j)
                acc[i][j] = __builtin_amdgcn_mfma_f32_16x16x32_bf16(af[i], bfr[j], acc[i][j], 0, 0, 0);
        __builtin_amdgcn_s_setprio(0);
    };

    const int NH = K >> 5;                  // half-steps (64 for K=2048)
    stage(0); stage(1); stage(2);           // 12 loads in flight
    for (int h = 0; h <= NH - 3; ++h) {
        asm volatile("s_waitcnt vmcnt(8)" ::: "memory");   // half h landed (h+1,h+2 flying)
        asm volatile("s_barrier" ::: "memory");            // all waves' chunks visible; slot h-1 free
        if (h < NH - 3) stage(h + 3);
        compute(h);
    }
    asm volatile("s_waitcnt vmcnt(4)" ::: "memory");
    asm volatile("s_barrier" ::: "memory");
    compute(NH - 2);
    asm volatile("s_waitcnt vmcnt(0)" ::: "memory");
    asm volatile("s_barrier" ::: "memory");
    compute(NH - 1);

    if (EPI == 0) {
        float* C = Cf + z * sCf;
#pragma unroll
        for (int i = 0; i < 8; ++i) {
            int m_b = m0 + wr * 128 + i * 16 + lhi * 4;
#pragma unroll
            for (int j = 0; j < 4; ++j) {
                int n = n0 + wc * 64 + j * 16 + llo;
#pragma unroll
                for (int r = 0; r < 4; ++r)
                    C[(long)(m_b + r) * D + n] = acc[i][j][r];
            }
        }
    } else if (EPI == 1) {
        u16* P = Cp + z * sCp;
#pragma unroll
        for (int i = 0; i < 8; ++i) {
            int m_b = m0 + wr * 128 + i * 16 + lhi * 4;
#pragma unroll
            for (int j = 0; j < 4; ++j) {
                int n = n0 + wc * 64 + j * 16 + llo;
                short4v pk;
#pragma unroll
                for (int r = 0; r < 4; ++r) {
                    float v = ((m_b + r) == n ? 1.f : 0.f) - acc[i][j][r];
                    pk[r] = (short)f2bf(v);
                }
                *(short4v*)((char*)P + ((long)((m_b >> 3) * D + n)) * 16 + (m_b & 7) * 2) = pk;
            }
        }
    } else if (EPI == 2) {
        float* X = Ef + z * DD;
        u16*   P = Cp + z * sCp;
#pragma unroll
        for (int i = 0; i < 8; ++i) {
            int m_b = m0 + wr * 128 + i * 16 + lhi * 4;
#pragma unroll
            for (int j = 0; j < 4; ++j) {
                int n = n0 + wc * 64 + j * 16 + llo;
                short4v pk;
#pragma unroll
                for (int r = 0; r < 4; ++r) {
                    long o = (long)(m_b + r) * D + n;
                    float v = X[o] + acc[i][j][r];
                    X[o] = v;
                    pk[r] = (short)f2bf(v);
                }
                *(short4v*)((char*)P + ((long)((m_b >> 3) * D + n)) * 16 + (m_b & 7) * 2) = pk;
            }
        }
    } else if (EPI == 4) {
        float lam = sqrtf(u[z * 16 + NPOW - 1]);
        float bb = 1.25f * lam + 0.05f, aa = 0.095f;
        float als = 2.f / (bb - aa);
        float bet = -(bb + aa) / (bb - aa);
        float t3  = (4.f * bet * bet - 3.f) * bet;
        float C2 = -4.f * als * als * als / t3;
        float C1 = -12.f * als * als * bet / t3;
        float C0 = -als * (12.f * bet * bet - 3.f) / t3;
        float* Xf = Ef + z * DD;
        u16*   P  = Cp + z * sCp;
#pragma unroll
        for (int i = 0; i < 8; ++i) {
            int m_b = m0 + wr * 128 + i * 16 + lhi * 4;
#pragma unroll
            for (int j = 0; j < 4; ++j) {
                int n = n0 + wc * 64 + j * 16 + llo;
                short4v pk;
#pragma unroll
                for (int r = 0; r < 4; ++r) {
                    long o = (long)(m_b + r) * D + n;
                    float eye = ((m_b + r) == n) ? 1.f : 0.f;
                    float v = C0 * eye + C1 * Xf[o] + C2 * acc[i][j][r];
                    Xf[o] = v;
                    pk[r] = (short)f2bf(v);
                }
                *(short4v*)((char*)P + ((long)((m_b >> 3) * D + n)) * 16 + (m_b & 7) * 2) = pk;
            }
        }
    } else {
        float uv[4];
#pragma unroll
        for (int j = 0; j < 4; ++j) uv[j] = u[z * D + n0 + wc * 64 + j * 16 + llo];
#pragma unroll
        for (int i = 0; i < 8; ++i) {
#pragma unroll
            for (int r = 0; r < 4; ++r) {
                int row = m0 + wr * 128 + i * 16 + lhi * 4 + r;
                float t = 0.f;
#pragma unroll
                for (int j = 0; j < 4; ++j) {
                    int n = n0 + wc * 64 + j * 16 + llo;
                    t += (acc[i][j][r] - 2.f * uv[j]) * Qf[(long)row * D + n];
                }
                t += __shfl_xor(t, 1);
                t += __shfl_xor(t, 2);
                t += __shfl_xor(t, 4);
                t += __shfl_xor(t, 8);
                if (llo == 0) atomicAdd(&acc2[row * 2 + z], t);
            }
        }
    }
}

// ---------------- launch ----------------

extern "C" void kernel_launch(void* const* d_in, const int* in_sizes, int n_in,
                              void* d_out, int out_size, void* d_ws, size_t ws_size,
                              hipStream_t stream) {
    const float* Q   = (const float*)d_in[0];
    const float* Xs  = (const float*)d_in[1];
    const int*   lab = (const int*)d_in[2];
    float* out = (float*)d_out;
    float* W   = (float*)d_ws;

    char* BIG = (char*)d_ws + (long)SMALL_FLOATS * 4;
    u16*  Sp   = (u16*)(BIG);                    // [S/8][D][8]          8.4 MB
    u16*  S01p = (u16*)(BIG + 8388608L);         // [2][S/8][D][8]      16.8 MB
    u16*  Rp   = (u16*)(BIG + 25165824L);        // [2] pack            16.8 MB
    u16*  Mp   = (u16*)(BIG + 41943040L);        // [2] pack            16.8 MB
    u16*  Xp0  = (u16*)(BIG + 58720256L);        // [2] pack            16.8 MB
    u16*  Xp1  = (u16*)(BIG + 75497472L);        // [2] pack            16.8 MB
    float* F32 = (float*)(BIG + 92274688L);      // [2][D][D] fp32      33.6 MB (Gram->M->X)
    u16*  Qp   = (u16*)(BIG);                    // [D/8][NQ][8] 67 MB, overlays Sp..Xp0-front (dead then)

    hipMemsetAsync(d_ws, 0, SMALL_FLOATS * sizeof(float), stream);

    k_counts<<<1, 256, 0, stream>>>(lab, W);
    k_colsums<<<dim3(D / 256, 16), 256, 0, stream>>>(Xs, lab, W);
    k_stats<<<D / 256, 256, 0, stream>>>(W);
    k_pack_S<<<dim3(D / 256, S / 8), 256, 0, stream>>>(Xs, lab, Sp, S01p);

    // Gram_c = (mask_c S)^T S  -> F32
    bgemm2<0><<<dim3(8, 8, 2), 512, 0, stream>>>(
        S01p, Sp, F32, nullptr, nullptr, DD, 0, DD, 0, D, S,
        nullptr, nullptr, nullptr);

    k_build_M<<<(int)(DD / 256), 256, 0, stream>>>(F32, W);

    for (int it = 0; it < NPOW; ++it)
        k_pow<<<dim3(D / 4, 2), 256, 0, stream>>>(F32, W, it);

    k_pack_M<<<dim3(D / 256, D / 8, 2), 256, 0, stream>>>(F32, Mp);

    // X0 = C0 I + C1 M + C2 M^2 (Chebyshev deg-3 init): one GEMM (M^2) + fused epilogue.
    bgemm2<4><<<dim3(8, 8, 2), 512, 0, stream>>>(
        Mp, Mp, nullptr, Xp0, F32, DD, DD, 0, DD, D, D,
        W + IDX_NORMS, nullptr, nullptr);

    u16* xp[2] = {Xp0, Xp1};
    int cur = 0;
    for (int it = 0; it < NNS; ++it) {
        // R = I - M X
        bgemm2<1><<<dim3(8, 8, 2), 512, 0, stream>>>(
            Mp, xp[cur], nullptr, Rp, nullptr, DD, DD, 0, DD, D, D,
            nullptr, nullptr, nullptr);
        // X += X^T R  (X symmetric), fp32 in-place + new pack
        bgemm2<2><<<dim3(8, 8, 2), 512, 0, stream>>>(
            xp[cur], Rp, nullptr, xp[cur ^ 1], F32, DD, DD, 0, DD, D, D,
            nullptr, nullptr, nullptr);
        cur ^= 1;
    }
    // P: fp32 in F32, bf16 pack in xp[cur]

    k_matvec_u<<<dim3(D / 4, 2), 256, 0, stream>>>(F32, W);
    k_dot<<<2, 256, 0, stream>>>(W);

    k_pack_Q<<<NQ, 256, 0, stream>>>(Q, Qp);

    // fused: acc2[n,z] = q^T P q - 2 (P mu)^T q
    bgemm2<3><<<dim3(8, 64, 2), 512, 0, stream>>>(
        Qp, xp[cur], nullptr, nullptr, nullptr, 0, DD, 0, 0, NQ, D,
        W + IDX_U, W + IDX_ACC, Q);

    k_finalize<<<NQ * 2 / 256, 256, 0, stream>>>(W, out);
}

// Round 5
// 1370.104 us; speedup vs baseline: 1.1204x; 1.1204x over previous
//
#include <hip/hip_runtime.h>

#define D   2048
#define S   2048
#define NQ  16384
#define DD  ((long)D * (long)D)

// ---- ws small-region layout (float indices) ----
#define IDX_N      0        // [2] class counts (atomic)
#define IDX_NORMS  16       // [2][16] power-iter norms (atomic)
#define IDX_S      48       // [2] mu^T P mu
#define IDX_SUM    256      // [2][2048] masked column sums (atomic)
#define IDX_MU     4608     // [2][2048] class means
#define IDX_MUF    8704     // [2048]   full mean
#define IDX_U      10752    // [2][2048] u = P mu
#define IDX_V      14848    // [2][2048] power vec ping
#define IDX_W2     18944    // [2][2048] power vec pong
#define IDX_ACC    32768    // [16384][2] logits accumulator (atomic)
#define SMALL_FLOATS 65536  // 256 KB zeroed region

#define NPOW 8
#define NNS  5

typedef unsigned short u16;
typedef __attribute__((ext_vector_type(8))) short short8;
typedef __attribute__((ext_vector_type(4))) short short4v;
typedef __attribute__((ext_vector_type(4))) float f32x4;

__device__ __forceinline__ u16 f2bf(float f) {
    unsigned u = __float_as_uint(f);
    u += 0x7fff + ((u >> 16) & 1);
    return (u16)(u >> 16);
}

__device__ __forceinline__ void gl16(const void* g, void* l) {
    __builtin_amdgcn_global_load_lds((const __attribute__((address_space(1))) void*)g,
                                     (__attribute__((address_space(3))) void*)l, 16, 0, 0);
}

// ---------------- small kernels ----------------

__global__ void k_counts(const int* __restrict__ lab, float* __restrict__ W) {
    int c0 = 0, c1 = 0;
    for (int i = threadIdx.x; i < S; i += 256) {
        int l = lab[i];
        c0 += (l == 0);
        c1 += (l == 1);
    }
    atomicAdd(&W[IDX_N + 0], (float)c0);
    atomicAdd(&W[IDX_N + 1], (float)c1);
}

__global__ void k_colsums(const float* __restrict__ X, const int* __restrict__ lab,
                          float* __restrict__ W) {
    int d  = blockIdx.x * 256 + threadIdx.x;
    int i0 = blockIdx.y * 128;
    float s0 = 0.f, s1 = 0.f;
    for (int i = i0; i < i0 + 128; ++i) {
        float v = X[(long)i * D + d];
        int   l = lab[i];
        s0 += (l == 0) ? v : 0.f;
        s1 += (l == 1) ? v : 0.f;
    }
    atomicAdd(&W[IDX_SUM + d],     s0);
    atomicAdd(&W[IDX_SUM + D + d], s1);
}

__global__ void k_stats(float* __restrict__ W) {
    int d = blockIdx.x * 256 + threadIdx.x;
    float n0 = W[IDX_N], n1 = W[IDX_N + 1];
    float s0 = W[IDX_SUM + d], s1 = W[IDX_SUM + D + d];
    W[IDX_MU + d]     = s0 / n0;
    W[IDX_MU + D + d] = s1 / n1;
    W[IDX_MUF + d]    = (s0 + s1) / (float)S;
    unsigned h = (unsigned)d * 2654435761u;
    float r = 0.5f + (float)((h >> 16) & 1023) / 1024.f;
    W[IDX_V + d]     = r;
    W[IDX_V + D + d] = r;
}

__global__ void k_build_M(float* __restrict__ AM, const float* __restrict__ W) {
    long idx = (long)blockIdx.x * 256 + threadIdx.x;
    int d = (int)(idx / D), e = (int)(idx % D);
    float n0 = W[IDX_N], n1 = W[IDX_N + 1];
    float mufd = W[IDX_MUF + d],     mufe = W[IDX_MUF + e];
    float m0d  = W[IDX_MU + d],      m0e  = W[IDX_MU + e];
    float m1d  = W[IDX_MU + D + d],  m1e  = W[IDX_MU + D + e];
    float a0 = AM[idx], a1 = AM[DD + idx];
    float task = (a0 + a1 - (float)S * mufd * mufe) * (1.f / (float)(S - 1));
    float c0 = (a0 - n0 * m0d * m0e) / (n0 - 1.f);
    float c1 = (a1 - n1 * m1d * m1e) / (n1 - 1.f);
    float l0 = fminf(n0 / (n0 + 1.f), 0.1f);
    float l1 = fminf(n1 / (n1 + 1.f), 0.1f);
    float eye = (d == e) ? 0.1f : 0.f;
    AM[idx]      = l0 * c0 + (1.f - l0) * task + eye;
    AM[DD + idx] = l1 * c1 + (1.f - l1) * task + eye;
}

__global__ void k_pow(const float* __restrict__ Mm, float* __restrict__ W, int it) {
    int z = blockIdx.y;
    const float* Mz = Mm + (long)z * DD;
    float* V  = W + IDX_V  + z * D;
    float* W2 = W + IDX_W2 + z * D;
    const float* in = (it & 1) ? W2 : V;
    float*       out = (it & 1) ? V  : W2;
    float sc = (it > 0) ? rsqrtf(W[IDX_NORMS + z * 16 + it - 1]) : 1.f;
    int wv = threadIdx.x >> 6, ln = threadIdx.x & 63;
    int d = blockIdx.x * 4 + wv;
    float p = 0.f;
    for (int e = ln; e < D; e += 64) p += Mz[(long)d * D + e] * in[e];
    for (int off = 32; off; off >>= 1) p += __shfl_down(p, off);
    if (ln == 0) {
        float w = p * sc;
        out[d] = w;
        atomicAdd(&W[IDX_NORMS + z * 16 + it], w * w);
    }
}

__global__ void k_matvec_u(const float* __restrict__ P, float* __restrict__ W) {
    int z = blockIdx.y;
    const float* Pz = P + (long)z * DD;
    const float* mu = W + IDX_MU + z * D;
    int wv = threadIdx.x >> 6, ln = threadIdx.x & 63;
    int d = blockIdx.x * 4 + wv;
    float p = 0.f;
    for (int e = ln; e < D; e += 64) p += Pz[(long)d * D + e] * mu[e];
    for (int off = 32; off; off >>= 1) p += __shfl_down(p, off);
    if (ln == 0) W[IDX_U + z * D + d] = p;
}

__global__ void k_dot(float* __restrict__ W) {
    int z = blockIdx.x;
    float t = 0.f;
    for (int d = threadIdx.x; d < D; d += 256)
        t += W[IDX_MU + z * D + d] * W[IDX_U + z * D + d];
    for (int off = 32; off; off >>= 1) t += __shfl_down(t, off);
    __shared__ float sm[4];
    int wv = threadIdx.x >> 6, ln = threadIdx.x & 63;
    if (ln == 0) sm[wv] = t;
    __syncthreads();
    if (threadIdx.x == 0) W[IDX_S + z] = sm[0] + sm[1] + sm[2] + sm[3];
}

__global__ void k_finalize(const float* __restrict__ W, float* __restrict__ out) {
    int idx = blockIdx.x * 256 + threadIdx.x;
    int z = idx & 1;
    out[idx] = -(W[IDX_ACC + idx] + W[IDX_S + z]);
}

// ---------------- pack kernels (k-packed bf16 layout: [K/8][cols][8]) ----------------

__global__ void k_pack_S(const float* __restrict__ Xs, const int* __restrict__ lab,
                         u16* __restrict__ Sp, u16* __restrict__ S01p) {
    int d = blockIdx.x * 256 + threadIdx.x;
    int a = blockIdx.y;                 // row-group i/8
    short8 p, p0, p1;
#pragma unroll
    for (int j = 0; j < 8; ++j) {
        int i = a * 8 + j;
        float v = Xs[(long)i * D + d];
        int   l = lab[i];
        short b = (short)f2bf(v);
        p[j]  = b;
        p0[j] = (l == 0) ? b : (short)0;
        p1[j] = (l == 1) ? b : (short)0;
    }
    long off = ((long)a * D + d) * 8;
    *(short8*)&Sp[off]        = p;
    *(short8*)&S01p[off]      = p0;
    *(short8*)&S01p[DD + off] = p1;
}

__global__ void k_pack_M(const float* __restrict__ Mf, u16* __restrict__ Mp) {
    int c = blockIdx.x * 256 + threadIdx.x;
    int a = blockIdx.y;
    int z = blockIdx.z;
    const float* src = Mf + (long)z * DD;
    u16* dst = Mp + (long)z * DD;
    short8 pk;
#pragma unroll
    for (int j = 0; j < 8; ++j) pk[j] = (short)f2bf(src[(long)(a * 8 + j) * D + c]);
    *(short8*)&dst[((long)a * D + c) * 8] = pk;
}

__global__ void k_pack_Q(const float* __restrict__ Q, u16* __restrict__ Qp) {
    int m = blockIdx.x;
    int t = threadIdx.x;                // k-group
    const float* row = Q + (long)m * D + t * 8;
    float4 v0 = *(const float4*)row;
    float4 v1 = *(const float4*)(row + 4);
    short8 pk;
    pk[0] = (short)f2bf(v0.x); pk[1] = (short)f2bf(v0.y);
    pk[2] = (short)f2bf(v0.z); pk[3] = (short)f2bf(v0.w);
    pk[4] = (short)f2bf(v1.x); pk[5] = (short)f2bf(v1.y);
    pk[6] = (short)f2bf(v1.z); pk[7] = (short)f2bf(v1.w);
    *(short8*)&Qp[((long)t * NQ + m) * 8] = pk;
}

// ---------------- bf16 MFMA GEMM, TM x 256 tile, counted-vmcnt pipeline ----------------
// 512 threads = 8 waves (2M x 4N); per-wave (TM/2) x 64 output; BK=32 per half-step.
// LDS: 4-slot ring; slot = A-half (TM x 32 x 2B) + B-half (16 KB).
//   TM=256: slot 32 KB, 128 KB total, grid (8, M/256, 2).
//   TM=128: slot 24 KB,  96 KB total, grid (8, M/128, 2) -> 256 blocks for D^3 (full CU coverage).
// Pipeline: 3 half-tiles prefetched via global_load_lds; per half-step: counted
// vmcnt (never 0 until tail), s_barrier, stage h+3, then compute. TM=256 compute
// is split into 2 phases (16-MFMA clusters) with a mid s_barrier + sched_barrier
// pins (m201 grain). EPI: 0=store fp32 C; 1=pack(I-acc); 2=X+=acc (fp32 RMW)+pack;
// 3=fused logits; 4=Chebyshev init X0=C0 I+C1 M+C2 acc (fp32 over Ef)+pack.
template <int TM, int EPI>
__global__ void __launch_bounds__(512)
bgemm2(const u16* __restrict__ Ap, const u16* __restrict__ Bp,
       float* __restrict__ Cf, u16* __restrict__ Cp, float* __restrict__ Ef,
       long sA, long sB, long sCf, long sCp,
       int lda, int K,
       const float* __restrict__ u, float* __restrict__ acc2,
       const float* __restrict__ Qf) {
    constexpr int MF    = TM / 32;            // m-frags per wave (8 or 4)
    constexpr int ASLAB = TM / 16;            // A slabs/slot (16 or 8)
    constexpr int LPT   = (ASLAB + 16) / 8;   // gl16 per thread per half-step (4 or 3)
    constexpr int ACQ   = TM / 64;            // A col-chunks (4 or 2)
    constexpr int SLOTB = TM * 64 + 16384;    // slot bytes
    constexpr int SLOTS = SLOTB / 2;          // slot shorts

    int z = blockIdx.z;
    const u16* A = Ap + z * sA;
    const u16* B = Bp + z * sB;

    // T1: bijective XCD swizzle over the per-z 2D grid (nwg % 8 == 0 for all our grids)
    int nwg = gridDim.x * gridDim.y;
    int id  = blockIdx.y * gridDim.x + blockIdx.x;
    int cpx = nwg >> 3;
    int swz = (id & 7) * cpx + (id >> 3);
    int bx = swz % gridDim.x, by = swz / gridDim.x;

    int n0 = bx * 256;
    int m0 = by * TM;
    int tid = threadIdx.x;
    int w = tid >> 6, lane = tid & 63;
    int wr = w >> 2, wc = w & 3;           // 2 x 4 wave grid
    int lhi = lane >> 4, llo = lane & 15;

    __shared__ short lds[TM * 128 + 32768];  // 4 slots

    f32x4 acc[MF][4];
#pragma unroll
    for (int i = 0; i < MF; ++i)
#pragma unroll
        for (int j = 0; j < 4; ++j) acc[i][j] = (f32x4)(0.f);

    // stage half-tile H (kgroups 4H..4H+3) into ring slot H&3
    auto stage = [&](int H) {
        char* ldsB = (char*)lds + (H & 3) * SLOTB;
#pragma unroll
        for (int q = 0; q < LPT; ++q) {
            int idq  = w * LPT + q;        // 0..8*LPT-1
            bool isB = idq >= ASLAB;
            int idr  = isB ? idq - ASLAB : idq;
            int kg   = isB ? (idr >> 2) : (idr / ACQ);
            int colq = isB ? (idr & 3)  : (idr % ACQ);
            long row = (long)(4 * H + kg);
            const u16* src = isB ? (B + (row * (long)D   + n0 + colq * 64) * 8)
                                 : (A + (row * (long)lda + m0 + colq * 64) * 8);
            char* dst = ldsB + (isB ? (TM * 64 + kg * 4096 + colq * 1024)
                                    : (kg * (TM * 16) + colq * 1024));
            gl16((const char*)src + lane * 16, dst);
        }
    };

    auto compute = [&](int h) {
        const short* slot = lds + (h & 3) * SLOTS;
        const short* As = slot + lhi * (TM * 8);
        const short* Bs = slot + TM * 32 + lhi * 2048;
        short8 af[4], bfr[4];
        if constexpr (TM == 256) {
            // phase A: m-frags 0..3
#pragma unroll
            for (int i = 0; i < 4; ++i)
                af[i] = *(const short8*)&As[(wr * 128 + i * 16 + llo) * 8];
#pragma unroll
            for (int j = 0; j < 4; ++j)
                bfr[j] = *(const short8*)&Bs[(wc * 64 + j * 16 + llo) * 8];
            __builtin_amdgcn_s_setprio(1);
#pragma unroll
            for (int i = 0; i < 4; ++i)
#pragma unroll
                for (int j = 0; j < 4; ++j)
                    acc[i][j] = __builtin_amdgcn_mfma_f32_16x16x32_bf16(af[i], bfr[j], acc[i][j], 0, 0, 0);
            __builtin_amdgcn_s_setprio(0);
            __builtin_amdgcn_sched_barrier(0);
            asm volatile("s_barrier" ::: "memory");
            // phase B: m-frags 4..7
#pragma unroll
            for (int i = 0; i < 4; ++i)
                af[i] = *(const short8*)&As[(wr * 128 + (i + 4) * 16 + llo) * 8];
            __builtin_amdgcn_s_setprio(1);
#pragma unroll
            for (int i = 0; i < 4; ++i)
#pragma unroll
                for (int j = 0; j < 4; ++j)
                    acc[i + 4][j] = __builtin_amdgcn_mfma_f32_16x16x32_bf16(af[i], bfr[j], acc[i + 4][j], 0, 0, 0);
            __builtin_amdgcn_s_setprio(0);
            __builtin_amdgcn_sched_barrier(0);
        } else {
#pragma unroll
            for (int i = 0; i < 4; ++i)
                af[i] = *(const short8*)&As[(wr * 64 + i * 16 + llo) * 8];
#pragma unroll
            for (int j = 0; j < 4; ++j)
                bfr[j] = *(const short8*)&Bs[(wc * 64 + j * 16 + llo) * 8];
            __builtin_amdgcn_s_setprio(1);
#pragma unroll
            for (int i = 0; i < 4; ++i)
#pragma unroll
                for (int j = 0; j < 4; ++j)
                    acc[i][j] = __builtin_amdgcn_mfma_f32_16x16x32_bf16(af[i], bfr[j], acc[i][j], 0, 0, 0);
            __builtin_amdgcn_s_setprio(0);
            __builtin_amdgcn_sched_barrier(0);
        }
    };

    const int NH = K >> 5;                  // half-steps (64 for K=2048)
    stage(0); stage(1); stage(2);           // 3*LPT loads in flight
    for (int h = 0; h <= NH - 3; ++h) {
        if constexpr (TM == 256)
            asm volatile("s_waitcnt vmcnt(8)" ::: "memory");   // half h landed (h+1,h+2 flying)
        else
            asm volatile("s_waitcnt vmcnt(6)" ::: "memory");
        asm volatile("s_barrier" ::: "memory");                // all chunks visible; slot h-1 free
        if (h < NH - 3) stage(h + 3);
        compute(h);
    }
    if constexpr (TM == 256)
        asm volatile("s_waitcnt vmcnt(4)" ::: "memory");
    else
        asm volatile("s_waitcnt vmcnt(3)" ::: "memory");
    asm volatile("s_barrier" ::: "memory");
    compute(NH - 2);
    asm volatile("s_waitcnt vmcnt(0)" ::: "memory");
    asm volatile("s_barrier" ::: "memory");
    compute(NH - 1);

    if (EPI == 0) {
        float* C = Cf + z * sCf;
#pragma unroll
        for (int i = 0; i < MF; ++i) {
            int m_b = m0 + wr * (TM / 2) + i * 16 + lhi * 4;
#pragma unroll
            for (int j = 0; j < 4; ++j) {
                int n = n0 + wc * 64 + j * 16 + llo;
#pragma unroll
                for (int r = 0; r < 4; ++r)
                    C[(long)(m_b + r) * D + n] = acc[i][j][r];
            }
        }
    } else if (EPI == 1) {
        u16* P = Cp + z * sCp;
#pragma unroll
        for (int i = 0; i < MF; ++i) {
            int m_b = m0 + wr * (TM / 2) + i * 16 + lhi * 4;
#pragma unroll
            for (int j = 0; j < 4; ++j) {
                int n = n0 + wc * 64 + j * 16 + llo;
                short4v pk;
#pragma unroll
                for (int r = 0; r < 4; ++r) {
                    float v = ((m_b + r) == n ? 1.f : 0.f) - acc[i][j][r];
                    pk[r] = (short)f2bf(v);
                }
                *(short4v*)((char*)P + ((long)((m_b >> 3) * D + n)) * 16 + (m_b & 7) * 2) = pk;
            }
        }
    } else if (EPI == 2) {
        float* X = Ef + z * DD;
        u16*   P = Cp + z * sCp;
#pragma unroll
        for (int i = 0; i < MF; ++i) {
            int m_b = m0 + wr * (TM / 2) + i * 16 + lhi * 4;
#pragma unroll
            for (int j = 0; j < 4; ++j) {
                int n = n0 + wc * 64 + j * 16 + llo;
                short4v pk;
#pragma unroll
                for (int r = 0; r < 4; ++r) {
                    long o = (long)(m_b + r) * D + n;
                    float v = X[o] + acc[i][j][r];
                    X[o] = v;
                    pk[r] = (short)f2bf(v);
                }
                *(short4v*)((char*)P + ((long)((m_b >> 3) * D + n)) * 16 + (m_b & 7) * 2) = pk;
            }
        }
    } else if (EPI == 4) {
        float lam = sqrtf(u[z * 16 + NPOW - 1]);
        float bb = 1.25f * lam + 0.05f, aa = 0.095f;
        float als = 2.f / (bb - aa);
        float bet = -(bb + aa) / (bb - aa);
        float t3  = (4.f * bet * bet - 3.f) * bet;
        float C2 = -4.f * als * als * als / t3;
        float C1 = -12.f * als * als * bet / t3;
        float C0 = -als * (12.f * bet * bet - 3.f) / t3;
        float* Xf = Ef + z * DD;
        u16*   P  = Cp + z * sCp;
#pragma unroll
        for (int i = 0; i < MF; ++i) {
            int m_b = m0 + wr * (TM / 2) + i * 16 + lhi * 4;
#pragma unroll
            for (int j = 0; j < 4; ++j) {
                int n = n0 + wc * 64 + j * 16 + llo;
                short4v pk;
#pragma unroll
                for (int r = 0; r < 4; ++r) {
                    long o = (long)(m_b + r) * D + n;
                    float eye = ((m_b + r) == n) ? 1.f : 0.f;
                    float v = C0 * eye + C1 * Xf[o] + C2 * acc[i][j][r];
                    Xf[o] = v;
                    pk[r] = (short)f2bf(v);
                }
                *(short4v*)((char*)P + ((long)((m_b >> 3) * D + n)) * 16 + (m_b & 7) * 2) = pk;
            }
        }
    } else {
        float uv[4];
#pragma unroll
        for (int j = 0; j < 4; ++j) uv[j] = u[z * D + n0 + wc * 64 + j * 16 + llo];
#pragma unroll
        for (int i = 0; i < MF; ++i) {
#pragma unroll
            for (int r = 0; r < 4; ++r) {
                int row = m0 + wr * (TM / 2) + i * 16 + lhi * 4 + r;
                float t = 0.f;
#pragma unroll
                for (int j = 0; j < 4; ++j) {
                    int n = n0 + wc * 64 + j * 16 + llo;
                    t += (acc[i][j][r] - 2.f * uv[j]) * Qf[(long)row * D + n];
                }
                t += __shfl_xor(t, 1);
                t += __shfl_xor(t, 2);
                t += __shfl_xor(t, 4);
                t += __shfl_xor(t, 8);
                if (llo == 0) atomicAdd(&acc2[row * 2 + z], t);
            }
        }
    }
}

// ---------------- launch ----------------

extern "C" void kernel_launch(void* const* d_in, const int* in_sizes, int n_in,
                              void* d_out, int out_size, void* d_ws, size_t ws_size,
                              hipStream_t stream) {
    const float* Q   = (const float*)d_in[0];
    const float* Xs  = (const float*)d_in[1];
    const int*   lab = (const int*)d_in[2];
    float* out = (float*)d_out;
    float* W   = (float*)d_ws;

    char* BIG = (char*)d_ws + (long)SMALL_FLOATS * 4;
    u16*  Sp   = (u16*)(BIG);                    // [S/8][D][8]          8.4 MB
    u16*  S01p = (u16*)(BIG + 8388608L);         // [2][S/8][D][8]      16.8 MB
    u16*  Rp   = (u16*)(BIG + 25165824L);        // [2] pack            16.8 MB
    u16*  Mp   = (u16*)(BIG + 41943040L);        // [2] pack            16.8 MB
    u16*  Xp0  = (u16*)(BIG + 58720256L);        // [2] pack            16.8 MB
    u16*  Xp1  = (u16*)(BIG + 75497472L);        // [2] pack            16.8 MB
    float* F32 = (float*)(BIG + 92274688L);      // [2][D][D] fp32      33.6 MB (Gram->M->X)
    u16*  Qp   = (u16*)(BIG);                    // [D/8][NQ][8] 67 MB, overlays Sp..Xp0-front (dead then)

    hipMemsetAsync(d_ws, 0, SMALL_FLOATS * sizeof(float), stream);

    k_counts<<<1, 256, 0, stream>>>(lab, W);
    k_colsums<<<dim3(D / 256, 16), 256, 0, stream>>>(Xs, lab, W);
    k_stats<<<D / 256, 256, 0, stream>>>(W);
    k_pack_S<<<dim3(D / 256, S / 8), 256, 0, stream>>>(Xs, lab, Sp, S01p);

    // Gram_c = (mask_c S)^T S  -> F32   (128x256 tile: 256 blocks, full CU coverage)
    bgemm2<128, 0><<<dim3(8, 16, 2), 512, 0, stream>>>(
        S01p, Sp, F32, nullptr, nullptr, DD, 0, DD, 0, D, S,
        nullptr, nullptr, nullptr);

    k_build_M<<<(int)(DD / 256), 256, 0, stream>>>(F32, W);

    for (int it = 0; it < NPOW; ++it)
        k_pow<<<dim3(D / 4, 2), 256, 0, stream>>>(F32, W, it);

    k_pack_M<<<dim3(D / 256, D / 8, 2), 256, 0, stream>>>(F32, Mp);

    // X0 = C0 I + C1 M + C2 M^2 (Chebyshev deg-3 init): one GEMM (M^2) + fused epilogue.
    bgemm2<128, 4><<<dim3(8, 16, 2), 512, 0, stream>>>(
        Mp, Mp, nullptr, Xp0, F32, DD, DD, 0, DD, D, D,
        W + IDX_NORMS, nullptr, nullptr);

    u16* xp[2] = {Xp0, Xp1};
    int cur = 0;
    for (int it = 0; it < NNS; ++it) {
        // R = I - M X
        bgemm2<128, 1><<<dim3(8, 16, 2), 512, 0, stream>>>(
            Mp, xp[cur], nullptr, Rp, nullptr, DD, DD, 0, DD, D, D,
            nullptr, nullptr, nullptr);
        // X += X^T R  (X symmetric), fp32 in-place + new pack
        bgemm2<128, 2><<<dim3(8, 16, 2), 512, 0, stream>>>(
            xp[cur], Rp, nullptr, xp[cur ^ 1], F32, DD, DD, 0, DD, D, D,
            nullptr, nullptr, nullptr);
        cur ^= 1;
    }
    // P: fp32 in F32, bf16 pack in xp[cur]

    k_matvec_u<<<dim3(D / 4, 2), 256, 0, stream>>>(F32, W);
    k_dot<<<2, 256, 0, stream>>>(W);

    k_pack_Q<<<NQ, 256, 0, stream>>>(Q, Qp);

    // fused: acc2[n,z] = q^T P q - 2 (P mu)^T q
    bgemm2<256, 3><<<dim3(8, 64, 2), 512, 0, stream>>>(
        Qp, xp[cur], nullptr, nullptr, nullptr, 0, DD, 0, 0, NQ, D,
        W + IDX_U, W + IDX_ACC, Q);

    k_finalize<<<NQ * 2 / 256, 256, 0, stream>>>(W, out);
}